// Round 5
// baseline (329.310 us; speedup 1.0000x reference)
//
#include <hip/hip_runtime.h>
#include <math.h>

typedef short s16x8 __attribute__((ext_vector_type(8)));
typedef float f32x4 __attribute__((ext_vector_type(4)));

#define MFMA(a, b, c) __builtin_amdgcn_mfma_f32_16x16x32_bf16(a, b, c, 0, 0, 0)

__device__ __forceinline__ float b2f(ushort u) {
    union { unsigned int i; float f; } v; v.i = ((unsigned int)u) << 16; return v.f;
}
__device__ __forceinline__ ushort f2b(float f) {
    union { float f; unsigned int i; } v; v.f = f;
    unsigned int r = v.i + 0x7fffu + ((v.i >> 16) & 1u);
    return (ushort)(r >> 16);
}
// pack 8 consecutive f32 (two float4) -> uint4 of 8 bf16
__device__ __forceinline__ uint4 pack8(const float4 a, const float4 b) {
    uint4 o;
    o.x = (unsigned int)f2b(a.x) | ((unsigned int)f2b(a.y) << 16);
    o.y = (unsigned int)f2b(a.z) | ((unsigned int)f2b(a.w) << 16);
    o.z = (unsigned int)f2b(b.x) | ((unsigned int)f2b(b.y) << 16);
    o.w = (unsigned int)f2b(b.z) | ((unsigned int)f2b(b.w) << 16);
    return o;
}

// ---------------------------------------------------------------------------
// K2: fused LN1 + cyclic-shift + window gather + QKV GEMM (f32 in, bf16 out).
// Grid 512: one 128-row A-tile per block, loops over the 3 N-tiles of 128.
// ---------------------------------------------------------------------------
__global__ __launch_bounds__(256) void k2_qkv_fused(
    const float* __restrict__ x, const float* __restrict__ g,
    const float* __restrict__ be, const float* __restrict__ qkv_w,
    const float* __restrict__ qkv_b, ushort* __restrict__ qkv)
{
    __shared__ __align__(16) ushort As[128][136];
    __shared__ __align__(16) ushort Bs[128][40];
    int tid = threadIdx.x;
    int m0 = blockIdx.x * 128;
    {   // Phase A: LN + shift + gather -> As (bf16)
        int row = tid >> 1, half = tid & 1;
        int tk = m0 + row;
        int wi = tk >> 7, t = tk & 127;
        int b = wi >> 8, wd = (wi >> 6) & 3, wh = (wi >> 3) & 7, ww = wi & 7;
        int td = t >> 6, th = (t >> 3) & 7, tw = t & 7;
        int d = (wd * 2 + td + 1) & 7;        // shifted coord -> source coord
        int h = (wh * 8 + th + 4) & 63;
        int w = (ww * 8 + tw + 4) & 63;
        long src = (((long)((b * 8 + d) * 64 + h)) * 64 + w) * 128 + half * 64;
        float vals[64];
        float s = 0.f, q = 0.f;
        #pragma unroll
        for (int i = 0; i < 16; ++i) {
            float4 u = *(const float4*)&x[src + i * 4];
            vals[i * 4 + 0] = u.x; vals[i * 4 + 1] = u.y;
            vals[i * 4 + 2] = u.z; vals[i * 4 + 3] = u.w;
            s += u.x + u.y + u.z + u.w;
            q += u.x * u.x + u.y * u.y + u.z * u.z + u.w * u.w;
        }
        s += __shfl_xor(s, 1);
        q += __shfl_xor(q, 1);
        float mean = s * (1.f / 128.f);
        float var = q * (1.f / 128.f) - mean * mean;
        float rstd = rsqrtf(var + 1e-5f);
        #pragma unroll
        for (int i = 0; i < 8; ++i) {
            ushort pk[8];
            #pragma unroll
            for (int j = 0; j < 8; ++j) {
                int c = half * 64 + i * 8 + j;
                pk[j] = f2b((vals[i * 8 + j] - mean) * rstd * g[c] + be[c]);
            }
            *(uint4*)&As[row][half * 64 + i * 8] = *(uint4*)pk;
        }
    }
    __syncthreads();
    int wv = tid >> 6, lane = tid & 63, li = lane & 15, quad = lane >> 4;
    int wm = wv >> 1, wn = wv & 1;
    for (int nb = 0; nb < 3; ++nb) {
        f32x4 acc[4][4] = {};
        for (int s = 0; s < 4; ++s) {
            #pragma unroll
            for (int i = 0; i < 2; ++i) {
                int c = tid + i * 256;
                int row = c >> 2, col8 = (c & 3) * 8;
                long wo = (long)(nb * 128 + row) * 128 + s * 32 + col8;
                float4 w0 = *(const float4*)&qkv_w[wo];
                float4 w1 = *(const float4*)&qkv_w[wo + 4];
                *(uint4*)&Bs[row][col8] = pack8(w0, w1);
            }
            __syncthreads();
            s16x8 a[4], bf[4];
            #pragma unroll
            for (int mi = 0; mi < 4; ++mi)
                a[mi] = *(const s16x8*)&As[wm * 64 + mi * 16 + li][s * 32 + quad * 8];
            #pragma unroll
            for (int ni = 0; ni < 4; ++ni)
                bf[ni] = *(const s16x8*)&Bs[wn * 64 + ni * 16 + li][quad * 8];
            #pragma unroll
            for (int mi = 0; mi < 4; ++mi)
                #pragma unroll
                for (int ni = 0; ni < 4; ++ni)
                    acc[mi][ni] = MFMA(a[mi], bf[ni], acc[mi][ni]);
            __syncthreads();
        }
        #pragma unroll
        for (int mi = 0; mi < 4; ++mi)
            #pragma unroll
            for (int ni = 0; ni < 4; ++ni) {
                int gcol = nb * 128 + wn * 64 + ni * 16 + li;
                float bias = qkv_b[gcol];
                float scale = (gcol < 128) ? 0.25f : 1.f;   // SCALE = 16^-0.5
                #pragma unroll
                for (int r = 0; r < 4; ++r) {
                    int grow = m0 + wm * 64 + mi * 16 + quad * 4 + r;
                    qkv[(long)grow * 384 + gcol] = f2b((acc[mi][ni][r] + bias) * scale);
                }
            }
    }
}

// ---------------------------------------------------------------------------
// K3: attention per (window, head). S=qk^T (+bias+mask), softmax, O=PV.
// qkv is bf16 (our intermediate); rpb is f32.
// ---------------------------------------------------------------------------
__global__ __launch_bounds__(256) void k3_attn(
    const ushort* __restrict__ qkv, const float* __restrict__ rpb,
    ushort* __restrict__ attnout)
{
    __shared__ __align__(16) ushort qs[128][40];
    __shared__ __align__(16) ushort ks[128][40];
    __shared__ __align__(16) ushort vt[16][136];
    __shared__ __align__(16) ushort ps[128][136];
    int bid = blockIdx.x;
    int wi = bid >> 3, head = bid & 7;
    int wd = (wi >> 6) & 3, wh = (wi >> 3) & 7, ww = wi & 7;
    int tid = threadIdx.x;
    int wv = tid >> 6, lane = tid & 63, li = lane & 15, quad = lane >> 4;
    {   // stage q, k (zero-padded K 16->32) and v transposed
        int token = tid >> 1, half = tid & 1;
        long base = ((long)(wi * 128 + token)) * 384 + head * 16 + half * 8;
        *(uint4*)&qs[token][half * 8] = *(const uint4*)&qkv[base];
        *(uint4*)&ks[token][half * 8] = *(const uint4*)&qkv[base + 128];
        uint4 z = {0, 0, 0, 0};
        *(uint4*)&qs[token][16 + half * 8] = z;
        *(uint4*)&ks[token][16 + half * 8] = z;
        uint4 vvv = *(const uint4*)&qkv[base + 256];
        const ushort* pv = (const ushort*)&vvv;
        #pragma unroll
        for (int j = 0; j < 8; ++j) vt[half * 8 + j][token] = pv[j];
    }
    __syncthreads();
    f32x4 sacc[2][8] = {};
    s16x8 a[2];
    #pragma unroll
    for (int mi = 0; mi < 2; ++mi) a[mi] = *(const s16x8*)&qs[wv * 32 + mi * 16 + li][quad * 8];
    #pragma unroll
    for (int ni = 0; ni < 8; ++ni) {
        s16x8 bf = *(const s16x8*)&ks[ni * 16 + li][quad * 8];
        #pragma unroll
        for (int mi = 0; mi < 2; ++mi) sacc[mi][ni] = MFMA(a[mi], bf, sacc[mi][ni]);
    }
    int regj[8], tdj[8], thj[8], twj[8];
    #pragma unroll
    for (int ni = 0; ni < 8; ++ni) {
        int j = ni * 16 + li;
        tdj[ni] = j >> 6; thj[ni] = (j >> 3) & 7; twj[ni] = j & 7;
        int d = wd * 2 + tdj[ni], h = wh * 8 + thj[ni], w = ww * 8 + twj[ni];
        int rd = (d < 6) ? 0 : (d < 7 ? 1 : 2);
        int rh = (h < 56) ? 0 : (h < 60 ? 1 : 2);
        int rw = (w < 56) ? 0 : (w < 60 ? 1 : 2);
        regj[ni] = rd * 9 + rh * 3 + rw;
    }
    #pragma unroll
    for (int mi = 0; mi < 2; ++mi) {
        #pragma unroll
        for (int r = 0; r < 4; ++r) {
            int i = wv * 32 + mi * 16 + quad * 4 + r;
            int tdi = i >> 6, thi = (i >> 3) & 7, twi = i & 7;
            int di = wd * 2 + tdi, hi = wh * 8 + thi, wwi = ww * 8 + twi;
            int rd = (di < 6) ? 0 : (di < 7 ? 1 : 2);
            int rh = (hi < 56) ? 0 : (hi < 60 ? 1 : 2);
            int rw = (wwi < 56) ? 0 : (wwi < 60 ? 1 : 2);
            int regi = rd * 9 + rh * 3 + rw;
            float sv[8];
            float rowmax = -1e30f;
            #pragma unroll
            for (int ni = 0; ni < 8; ++ni) {
                int rpi = (tdi - tdj[ni] + 1) * 225 + (thi - thj[ni] + 7) * 15 + (twi - twj[ni] + 7);
                float v = sacc[mi][ni][r] + rpb[rpi * 8 + head];
                if (regi != regj[ni]) v -= 100.f;
                sv[ni] = v;
                rowmax = fmaxf(rowmax, v);
            }
            #pragma unroll
            for (int m = 1; m < 16; m <<= 1) rowmax = fmaxf(rowmax, __shfl_xor(rowmax, m));
            float sum = 0.f;
            #pragma unroll
            for (int ni = 0; ni < 8; ++ni) { sv[ni] = __expf(sv[ni] - rowmax); sum += sv[ni]; }
            #pragma unroll
            for (int m = 1; m < 16; m <<= 1) sum += __shfl_xor(sum, m);
            float inv = 1.f / sum;
            #pragma unroll
            for (int ni = 0; ni < 8; ++ni) ps[i][ni * 16 + li] = f2b(sv[ni] * inv);
        }
    }
    __syncthreads();
    f32x4 pacc[2] = {};
    #pragma unroll
    for (int kk = 0; kk < 4; ++kk) {
        s16x8 bv = *(const s16x8*)&vt[li][kk * 32 + quad * 8];
        #pragma unroll
        for (int mi = 0; mi < 2; ++mi) {
            s16x8 ap = *(const s16x8*)&ps[wv * 32 + mi * 16 + li][kk * 32 + quad * 8];
            pacc[mi] = MFMA(ap, bv, pacc[mi]);
        }
    }
    #pragma unroll
    for (int mi = 0; mi < 2; ++mi)
        #pragma unroll
        for (int r = 0; r < 4; ++r) {
            int i = wv * 32 + mi * 16 + quad * 4 + r;
            attnout[((long)(wi * 128 + i)) * 128 + head * 16 + li] = f2b(pacc[mi][r]);
        }
}

// ---------------------------------------------------------------------------
// K4: proj GEMM + bias + window reverse + unshift + residual -> x1 (bf16)
// ao bf16; proj_w/proj_b/x are f32.
// ---------------------------------------------------------------------------
__global__ __launch_bounds__(256) void k4_proj(
    const ushort* __restrict__ ao, const float* __restrict__ proj_w,
    const float* __restrict__ proj_b, const float* __restrict__ x,
    ushort* __restrict__ x1)
{
    __shared__ __align__(16) ushort As[128][40];
    __shared__ __align__(16) ushort Bs[128][40];
    int tid = threadIdx.x;
    int m0 = blockIdx.x * 128;
    int wv = tid >> 6, lane = tid & 63, li = lane & 15, quad = lane >> 4;
    int wm = wv >> 1, wn = wv & 1;
    f32x4 acc[4][4] = {};
    for (int s = 0; s < 4; ++s) {
        #pragma unroll
        for (int i = 0; i < 2; ++i) {
            int c = tid + i * 256;
            int row = c >> 2, col8 = (c & 3) * 8;
            *(uint4*)&As[row][col8] = *(const uint4*)&ao[(long)(m0 + row) * 128 + s * 32 + col8];
            long wo = (long)row * 128 + s * 32 + col8;
            float4 w0 = *(const float4*)&proj_w[wo];
            float4 w1 = *(const float4*)&proj_w[wo + 4];
            *(uint4*)&Bs[row][col8] = pack8(w0, w1);
        }
        __syncthreads();
        s16x8 a[4], bf[4];
        #pragma unroll
        for (int mi = 0; mi < 4; ++mi) a[mi] = *(const s16x8*)&As[wm * 64 + mi * 16 + li][quad * 8];
        #pragma unroll
        for (int ni = 0; ni < 4; ++ni) bf[ni] = *(const s16x8*)&Bs[wn * 64 + ni * 16 + li][quad * 8];
        #pragma unroll
        for (int mi = 0; mi < 4; ++mi)
            #pragma unroll
            for (int ni = 0; ni < 4; ++ni)
                acc[mi][ni] = MFMA(a[mi], bf[ni], acc[mi][ni]);
        __syncthreads();
    }
    #pragma unroll
    for (int mi = 0; mi < 4; ++mi) {
        #pragma unroll
        for (int r = 0; r < 4; ++r) {
            int grow = m0 + wm * 64 + mi * 16 + quad * 4 + r;
            int wi2 = grow >> 7, t = grow & 127;
            int b = wi2 >> 8, wd = (wi2 >> 6) & 3, wh = (wi2 >> 3) & 7, ww = wi2 & 7;
            int td = t >> 6, th = (t >> 3) & 7, tw = t & 7;
            int d = (wd * 2 + td + 1) & 7, h = (wh * 8 + th + 4) & 63, w = (ww * 8 + tw + 4) & 63;
            long di = (((long)((b * 8 + d) * 64 + h)) * 64 + w) * 128;
            #pragma unroll
            for (int ni = 0; ni < 4; ++ni) {
                int gcol = wn * 64 + ni * 16 + li;
                float v = acc[mi][ni][r] + proj_b[gcol] + x[di + gcol];
                x1[di + gcol] = f2b(v);
            }
        }
    }
}

// ---------------------------------------------------------------------------
// K5: fused MLP: LN2 + FC1 + exact gelu + FC2 + residual. x1 bf16; weights f32
// (converted during staging); FINAL OUTPUT IS FLOAT32.
// ---------------------------------------------------------------------------
__global__ __launch_bounds__(256) void k5_mlp(
    const ushort* __restrict__ x1, const float* __restrict__ g2,
    const float* __restrict__ be2, const float* __restrict__ fc1_w,
    const float* __restrict__ fc1_b, const float* __restrict__ fc2_w,
    const float* __restrict__ fc2_b, float* __restrict__ out)
{
    __shared__ __align__(16) ushort xs[64][136];
    __shared__ __align__(16) ushort hs[64][136];
    __shared__ __align__(16) ushort wt[128][40];
    __shared__ float redS[4][64];
    __shared__ float redQ[4][64];
    int tid = threadIdx.x;
    int m0 = blockIdx.x * 64;
    int wv = tid >> 6, lane = tid & 63, li = lane & 15, quad = lane >> 4;
    int wm = wv >> 1, wn = wv & 1;
    {   // LN2: token = tid&63, 4 column-parts of 32
        int token = tid & 63, part = tid >> 6;
        float vals[32];
        float s = 0.f, q = 0.f;
        #pragma unroll
        for (int i = 0; i < 4; ++i) {
            uint4 u = *(const uint4*)&x1[(long)(m0 + token) * 128 + part * 32 + i * 8];
            const ushort* p = (const ushort*)&u;
            #pragma unroll
            for (int j = 0; j < 8; ++j) { float f = b2f(p[j]); vals[i * 8 + j] = f; s += f; q += f * f; }
        }
        redS[part][token] = s; redQ[part][token] = q;
        __syncthreads();
        float st = 0.f, qt = 0.f;
        #pragma unroll
        for (int p2 = 0; p2 < 4; ++p2) { st += redS[p2][token]; qt += redQ[p2][token]; }
        float mean = st * (1.f / 128.f);
        float var = qt * (1.f / 128.f) - mean * mean;
        float rstd = rsqrtf(var + 1e-5f);
        #pragma unroll
        for (int i = 0; i < 4; ++i) {
            ushort packed[8];
            #pragma unroll
            for (int j = 0; j < 8; ++j) {
                int c = part * 32 + i * 8 + j;
                packed[j] = f2b((vals[i * 8 + j] - mean) * rstd * g2[c] + be2[c]);
            }
            *(uint4*)&xs[token][part * 32 + i * 8] = *(uint4*)packed;
        }
    }
    __syncthreads();

    f32x4 yacc[2][4] = {};
    for (int hc = 0; hc < 4; ++hc) {
        f32x4 hacc[2][4] = {};
        for (int kk = 0; kk < 4; ++kk) {          // GEMM1: h = xs @ fc1_w[hc]^T
            #pragma unroll
            for (int i = 0; i < 2; ++i) {
                int c = tid + i * 256, row = c >> 2, col8 = (c & 3) * 8;
                long wo = (long)(hc * 128 + row) * 128 + kk * 32 + col8;
                float4 w0 = *(const float4*)&fc1_w[wo];
                float4 w1 = *(const float4*)&fc1_w[wo + 4];
                *(uint4*)&wt[row][col8] = pack8(w0, w1);
            }
            __syncthreads();
            s16x8 a[2], bf[4];
            #pragma unroll
            for (int mi = 0; mi < 2; ++mi) a[mi] = *(const s16x8*)&xs[wm * 32 + mi * 16 + li][kk * 32 + quad * 8];
            #pragma unroll
            for (int ni = 0; ni < 4; ++ni) bf[ni] = *(const s16x8*)&wt[wn * 64 + ni * 16 + li][quad * 8];
            #pragma unroll
            for (int mi = 0; mi < 2; ++mi)
                #pragma unroll
                for (int ni = 0; ni < 4; ++ni)
                    hacc[mi][ni] = MFMA(a[mi], bf[ni], hacc[mi][ni]);
            __syncthreads();
        }
        #pragma unroll
        for (int mi = 0; mi < 2; ++mi)            // exact gelu -> hs (bf16)
            #pragma unroll
            for (int ni = 0; ni < 4; ++ni) {
                int col = wn * 64 + ni * 16 + li;
                float bb = fc1_b[hc * 128 + col];
                #pragma unroll
                for (int r = 0; r < 4; ++r) {
                    int row = wm * 32 + mi * 16 + quad * 4 + r;
                    float v = hacc[mi][ni][r] + bb;
                    float ge = 0.5f * v * (1.f + erff(v * 0.70710678118f));
                    hs[row][col] = f2b(ge);
                }
            }
        __syncthreads();
        for (int kk = 0; kk < 4; ++kk) {          // GEMM2: y += hs @ fc2_w[:,hc]^T
            #pragma unroll
            for (int i = 0; i < 2; ++i) {
                int c = tid + i * 256, row = c >> 2, col8 = (c & 3) * 8;
                long wo = (long)row * 512 + hc * 128 + kk * 32 + col8;
                float4 w0 = *(const float4*)&fc2_w[wo];
                float4 w1 = *(const float4*)&fc2_w[wo + 4];
                *(uint4*)&wt[row][col8] = pack8(w0, w1);
            }
            __syncthreads();
            s16x8 a[2], bf[4];
            #pragma unroll
            for (int mi = 0; mi < 2; ++mi) a[mi] = *(const s16x8*)&hs[wm * 32 + mi * 16 + li][kk * 32 + quad * 8];
            #pragma unroll
            for (int ni = 0; ni < 4; ++ni) bf[ni] = *(const s16x8*)&wt[wn * 64 + ni * 16 + li][quad * 8];
            #pragma unroll
            for (int mi = 0; mi < 2; ++mi)
                #pragma unroll
                for (int ni = 0; ni < 4; ++ni)
                    yacc[mi][ni] = MFMA(a[mi], bf[ni], yacc[mi][ni]);
            __syncthreads();
        }
    }
    #pragma unroll
    for (int mi = 0; mi < 2; ++mi)
        #pragma unroll
        for (int ni = 0; ni < 4; ++ni) {
            int col = wn * 64 + ni * 16 + li;
            float fb = fc2_b[col];
            #pragma unroll
            for (int r = 0; r < 4; ++r) {
                int row = wm * 32 + mi * 16 + quad * 4 + r;
                long idx = (long)(m0 + row) * 128 + col;
                out[idx] = b2f(x1[idx]) + yacc[mi][ni][r] + fb;   // FLOAT32 store
            }
        }
}

// ---------------------------------------------------------------------------
// Inputs f32, OUTPUT f32 (d_out = 33.5 MB). Buffer plan:
//   K2: x (f32)            -> qkv bf16 @ ws+0 (50.3 MB)
//   K3: qkv                -> attn bf16 @ d_out[0..16.8MB) (scratch)
//   K4: attn(d_out), x     -> x1 bf16 @ ws+0 (qkv dead)
//   K5: x1 (ws)            -> final f32 @ d_out (overwrites scratch; K4 done)
// ---------------------------------------------------------------------------
extern "C" void kernel_launch(void* const* d_in, const int* in_sizes, int n_in,
                              void* d_out, int out_size, void* d_ws, size_t ws_size,
                              hipStream_t stream)
{
    (void)in_sizes; (void)n_in; (void)out_size; (void)ws_size;
    const float* x      = (const float*)d_in[0];
    const float* qkv_w  = (const float*)d_in[1];
    const float* qkv_b  = (const float*)d_in[2];
    const float* proj_w = (const float*)d_in[3];
    const float* proj_b = (const float*)d_in[4];
    const float* rpb    = (const float*)d_in[5];
    const float* ln1_g  = (const float*)d_in[6];
    const float* ln1_b  = (const float*)d_in[7];
    const float* ln2_g  = (const float*)d_in[8];
    const float* ln2_b  = (const float*)d_in[9];
    const float* fc1_w  = (const float*)d_in[10];
    const float* fc1_b  = (const float*)d_in[11];
    const float* fc2_w  = (const float*)d_in[12];
    const float* fc2_b  = (const float*)d_in[13];
    float* out = (float*)d_out;

    ushort* qkvb = (ushort*)d_ws;          // 50.3 MB (65536 x 384) bf16
    ushort* aob  = (ushort*)d_out;         // first 16.8 MB of d_out as scratch
    ushort* x1b  = (ushort*)d_ws;          // 16.8 MB, aliases dead qkv

    hipLaunchKernelGGL(k2_qkv_fused, dim3(512), dim3(256), 0, stream,
                       x, ln1_g, ln1_b, qkv_w, qkv_b, qkvb);
    hipLaunchKernelGGL(k3_attn, dim3(4096), dim3(256), 0, stream, qkvb, rpb, aob);
    hipLaunchKernelGGL(k4_proj, dim3(512), dim3(256), 0, stream, aob, proj_w, proj_b, x, x1b);
    hipLaunchKernelGGL(k5_mlp, dim3(1024), dim3(256), 0, stream,
                       x1b, ln2_g, ln2_b, fc1_w, fc1_b, fc2_w, fc2_b, out);
}

// Round 7
// 287.958 us; speedup vs baseline: 1.1436x; 1.1436x over previous
//
#include <hip/hip_runtime.h>
#include <math.h>

typedef short s16x8 __attribute__((ext_vector_type(8)));
typedef float f32x4 __attribute__((ext_vector_type(4)));

#define MFMA(a, b, c)   __builtin_amdgcn_mfma_f32_16x16x32_bf16(a, b, c, 0, 0, 0)

__device__ __forceinline__ float b2f(ushort u) {
    union { unsigned int i; float f; } v; v.i = ((unsigned int)u) << 16; return v.f;
}
__device__ __forceinline__ ushort f2b(float f) {
    union { float f; unsigned int i; } v; v.f = f;
    unsigned int r = v.i + 0x7fffu + ((v.i >> 16) & 1u);
    return (ushort)(r >> 16);
}

// ---------------------------------------------------------------------------
// K0a: blocks [0,256): convert qkv_w+proj_w f32->bf16 into T.
//      blocks [256,320): build combined rel-pos-bias + shifted-window-mask
//      table bm[cls][head][i][j] (bf16) at T+65536.
// ---------------------------------------------------------------------------
__global__ __launch_bounds__(256) void k0a_prep(
    const float* __restrict__ qkv_w, const float* __restrict__ proj_w,
    const float* __restrict__ rpb, ushort* __restrict__ T)
{
    int tid = threadIdx.x;
    if (blockIdx.x < 256) {
        int idx = blockIdx.x * 256 + tid;          // [0, 65536)
        float v = (idx < 49152) ? qkv_w[idx] : proj_w[idx - 49152];
        T[idx] = f2b(v);
        return;
    }
    int bi = blockIdx.x - 256;                      // [0,64) = cls*8+head
    int cls = bi >> 3, head = bi & 7;
    int ed = (cls >> 2) & 1, eh = (cls >> 1) & 1, ew = cls & 1;
    int j = tid & 127;
    int tdj = j >> 6, thj = (j >> 3) & 7, twj = j & 7;
    int regj = (ed ? (tdj + 1) : 0) * 9
             + (eh ? ((thj < 4) ? 1 : 2) : 0) * 3
             + (ew ? ((twj < 4) ? 1 : 2) : 0);
    ushort* bm = T + 65536 + (long)bi * 16384;
    for (int ii = 0; ii < 64; ++ii) {
        int i = (tid >> 7) * 64 + ii;
        int tdi = i >> 6, thi = (i >> 3) & 7, twi = i & 7;
        int regi = (ed ? (tdi + 1) : 0) * 9
                 + (eh ? ((thi < 4) ? 1 : 2) : 0) * 3
                 + (ew ? ((twi < 4) ? 1 : 2) : 0);
        int rpi = (tdi - tdj + 1) * 225 + (thi - thj + 7) * 15 + (twi - twj + 7);
        float v = rpb[rpi * 8 + head] + ((regi != regj) ? -100.f : 0.f);
        bm[i * 128 + j] = f2b(v);
    }
}

// K0b: convert fc1_w + fc2_w f32->bf16 into wf (dead-qkv region of ws).
__global__ __launch_bounds__(256) void k0b_wconv(
    const float* __restrict__ fc1_w, const float* __restrict__ fc2_w,
    ushort* __restrict__ wf)
{
    int idx = blockIdx.x * 256 + threadIdx.x;       // [0, 131072)
    float v = (idx < 65536) ? fc1_w[idx] : fc2_w[idx - 65536];
    wf[idx] = f2b(v);
}

// ---------------------------------------------------------------------------
// K2: fused LN1 + cyclic-shift + window gather + QKV GEMM.
// A staged in LDS (one sync); B-fragments direct from global bf16 weights.
// Output head-major: qkv[((mat*8+head)*65536 + token)*16 + dd], q scaled.
// ---------------------------------------------------------------------------
__global__ __launch_bounds__(256) void k2_qkv(
    const float* __restrict__ x, const float* __restrict__ g,
    const float* __restrict__ be, const ushort* __restrict__ wq,
    const float* __restrict__ qkv_b, ushort* __restrict__ qkv)
{
    __shared__ __align__(16) ushort As[128][136];
    int tid = threadIdx.x;
    int m0 = blockIdx.x * 128;
    {   // LN + shift + gather -> As (2 threads per row)
        int row = tid >> 1, half = tid & 1;
        int tk = m0 + row;
        int wi = tk >> 7, t = tk & 127;
        int b = wi >> 8, wd = (wi >> 6) & 3, wh = (wi >> 3) & 7, ww = wi & 7;
        int td = t >> 6, th = (t >> 3) & 7, tw = t & 7;
        int d = (wd * 2 + td + 1) & 7;
        int h = (wh * 8 + th + 4) & 63;
        int w = (ww * 8 + tw + 4) & 63;
        long src = (((long)((b * 8 + d) * 64 + h)) * 64 + w) * 128 + half * 64;
        float vals[64];
        float s = 0.f, q = 0.f;
        #pragma unroll
        for (int i = 0; i < 16; ++i) {
            float4 u = *(const float4*)&x[src + i * 4];
            vals[i * 4 + 0] = u.x; vals[i * 4 + 1] = u.y;
            vals[i * 4 + 2] = u.z; vals[i * 4 + 3] = u.w;
            s += u.x + u.y + u.z + u.w;
            q += u.x * u.x + u.y * u.y + u.z * u.z + u.w * u.w;
        }
        s += __shfl_xor(s, 1);
        q += __shfl_xor(q, 1);
        float mean = s * (1.f / 128.f);
        float rstd = rsqrtf(q * (1.f / 128.f) - mean * mean + 1e-5f);
        #pragma unroll
        for (int i = 0; i < 8; ++i) {
            ushort pk[8];
            #pragma unroll
            for (int jj = 0; jj < 8; ++jj) {
                int c = half * 64 + i * 8 + jj;
                pk[jj] = f2b((vals[i * 8 + jj] - mean) * rstd * g[c] + be[c]);
            }
            *(uint4*)&As[row][half * 64 + i * 8] = *(uint4*)pk;
        }
    }
    __syncthreads();
    int wv = tid >> 6, lane = tid & 63, li = lane & 15, quad = lane >> 4;
    int wm = wv >> 1, wn = wv & 1;
    for (int nb = 0; nb < 3; ++nb) {
        f32x4 acc[4][4] = {};
        for (int s = 0; s < 4; ++s) {
            s16x8 a[4], bw[4];
            #pragma unroll
            for (int mi = 0; mi < 4; ++mi)
                a[mi] = *(const s16x8*)&As[wm * 64 + mi * 16 + li][s * 32 + quad * 8];
            #pragma unroll
            for (int ni = 0; ni < 4; ++ni)
                bw[ni] = *(const s16x8*)&wq[(long)(nb * 128 + wn * 64 + ni * 16 + li) * 128
                                            + s * 32 + quad * 8];
            #pragma unroll
            for (int mi = 0; mi < 4; ++mi)
                #pragma unroll
                for (int ni = 0; ni < 4; ++ni)
                    acc[mi][ni] = MFMA(a[mi], bw[ni], acc[mi][ni]);
        }
        #pragma unroll
        for (int mi = 0; mi < 4; ++mi)
            #pragma unroll
            for (int ni = 0; ni < 4; ++ni) {
                int gcol = nb * 128 + wn * 64 + ni * 16 + li;
                int mat = gcol >> 7, hd = (gcol >> 4) & 7;
                float bias = qkv_b[gcol];
                float scale = (mat == 0) ? 0.25f : 1.f;   // SCALE = 16^-0.5
                #pragma unroll
                for (int r = 0; r < 4; ++r) {
                    int grow = m0 + wm * 64 + mi * 16 + quad * 4 + r;
                    qkv[((long)(mat * 8 + hd) * 65536 + grow) * 16 + li] =
                        f2b((acc[mi][ni][r] + bias) * scale);
                }
            }
    }
}

// ---------------------------------------------------------------------------
// K3: attention per (window, head). QK^T via 16x16x32 MFMA (d=16 zero-padded
// to 32), bias+mask from precomputed bm table, softmax, PV via 16x16x32.
// ---------------------------------------------------------------------------
__global__ __launch_bounds__(256) void k3_attn(
    const ushort* __restrict__ qkv, const ushort* __restrict__ bm,
    ushort* __restrict__ ao)
{
    __shared__ __align__(16) ushort qs[128][40];
    __shared__ __align__(16) ushort ks[128][40];
    __shared__ __align__(16) ushort vt[16][136];
    __shared__ __align__(16) ushort ps[128][136];
    int bid = blockIdx.x;
    int wi = bid >> 3, head = bid & 7;
    int wd = (wi >> 6) & 3, wh = (wi >> 3) & 7, ww = wi & 7;
    int cls = ((wd == 3) << 2) | ((wh == 7) << 1) | (ww == 7);
    long bmbase = (long)(cls * 8 + head) * 16384;
    int tid = threadIdx.x;
    int wv = tid >> 6, lane = tid & 63, li = lane & 15, quad = lane >> 4;
    {   // coalesced staging from head-major qkv; zero-pad K 16->32
        int token = tid >> 1, dd0 = (tid & 1) * 8;
        long tb = (long)(wi * 128 + token) * 16 + dd0;
        uint4 qv = *(const uint4*)&qkv[(long)head * 1048576 + tb];
        uint4 kv = *(const uint4*)&qkv[(long)(8 + head) * 1048576 + tb];
        uint4 vv = *(const uint4*)&qkv[(long)(16 + head) * 1048576 + tb];
        uint4 z = {0, 0, 0, 0};
        *(uint4*)&qs[token][dd0] = qv;
        *(uint4*)&ks[token][dd0] = kv;
        *(uint4*)&qs[token][16 + dd0] = z;
        *(uint4*)&ks[token][16 + dd0] = z;
        const ushort* pv = (const ushort*)&vv;
        #pragma unroll
        for (int j = 0; j < 8; ++j) vt[dd0 + j][token] = pv[j];
    }
    __syncthreads();
    f32x4 sacc[2][8] = {};
    s16x8 a[2];
    #pragma unroll
    for (int mi = 0; mi < 2; ++mi)
        a[mi] = *(const s16x8*)&qs[wv * 32 + mi * 16 + li][quad * 8];
    #pragma unroll
    for (int ni = 0; ni < 8; ++ni) {
        s16x8 bf = *(const s16x8*)&ks[ni * 16 + li][quad * 8];
        #pragma unroll
        for (int mi = 0; mi < 2; ++mi) sacc[mi][ni] = MFMA(a[mi], bf, sacc[mi][ni]);
    }
    #pragma unroll
    for (int mi = 0; mi < 2; ++mi) {
        #pragma unroll
        for (int r = 0; r < 4; ++r) {
            int i = wv * 32 + mi * 16 + quad * 4 + r;
            float sv[8];
            float rowmax = -1e30f;
            #pragma unroll
            for (int ni = 0; ni < 8; ++ni) {
                float v = sacc[mi][ni][r] + b2f(bm[bmbase + i * 128 + ni * 16 + li]);
                sv[ni] = v;
                rowmax = fmaxf(rowmax, v);
            }
            #pragma unroll
            for (int m = 1; m < 16; m <<= 1) rowmax = fmaxf(rowmax, __shfl_xor(rowmax, m));
            float sum = 0.f;
            #pragma unroll
            for (int ni = 0; ni < 8; ++ni) { sv[ni] = __expf(sv[ni] - rowmax); sum += sv[ni]; }
            #pragma unroll
            for (int m = 1; m < 16; m <<= 1) sum += __shfl_xor(sum, m);
            float inv = 1.f / sum;
            #pragma unroll
            for (int ni = 0; ni < 8; ++ni) ps[i][ni * 16 + li] = f2b(sv[ni] * inv);
        }
    }
    __syncthreads();
    f32x4 pacc[2] = {};
    #pragma unroll
    for (int kk = 0; kk < 4; ++kk) {
        s16x8 bv = *(const s16x8*)&vt[li][kk * 32 + quad * 8];
        #pragma unroll
        for (int mi = 0; mi < 2; ++mi) {
            s16x8 ap = *(const s16x8*)&ps[wv * 32 + mi * 16 + li][kk * 32 + quad * 8];
            pacc[mi] = MFMA(ap, bv, pacc[mi]);
        }
    }
    #pragma unroll
    for (int mi = 0; mi < 2; ++mi)
        #pragma unroll
        for (int r = 0; r < 4; ++r) {
            int i = wv * 32 + mi * 16 + quad * 4 + r;
            ao[((long)(wi * 128 + i)) * 128 + head * 16 + li] = f2b(pacc[mi][r]);
        }
}

// ---------------------------------------------------------------------------
// K4: proj GEMM + bias + window reverse + unshift + residual -> x1 (bf16).
// A (ao) staged coalesced; B direct from global bf16 proj weights.
// ---------------------------------------------------------------------------
__global__ __launch_bounds__(256) void k4_proj(
    const ushort* __restrict__ ao, const ushort* __restrict__ wp,
    const float* __restrict__ proj_b, const float* __restrict__ x,
    ushort* __restrict__ x1)
{
    __shared__ __align__(16) ushort As[128][136];
    int tid = threadIdx.x;
    int m0 = blockIdx.x * 128;
    #pragma unroll
    for (int i = 0; i < 8; ++i) {
        int slot = tid + i * 256;
        int row = slot >> 4, col8 = (slot & 15) * 8;
        *(uint4*)&As[row][col8] = *(const uint4*)&ao[(long)(m0 + row) * 128 + col8];
    }
    __syncthreads();
    int wv = tid >> 6, lane = tid & 63, li = lane & 15, quad = lane >> 4;
    int wm = wv >> 1, wn = wv & 1;
    f32x4 acc[4][4] = {};
    for (int s = 0; s < 4; ++s) {
        s16x8 a[4], bw[4];
        #pragma unroll
        for (int mi = 0; mi < 4; ++mi)
            a[mi] = *(const s16x8*)&As[wm * 64 + mi * 16 + li][s * 32 + quad * 8];
        #pragma unroll
        for (int ni = 0; ni < 4; ++ni)
            bw[ni] = *(const s16x8*)&wp[(long)(wn * 64 + ni * 16 + li) * 128 + s * 32 + quad * 8];
        #pragma unroll
        for (int mi = 0; mi < 4; ++mi)
            #pragma unroll
            for (int ni = 0; ni < 4; ++ni)
                acc[mi][ni] = MFMA(a[mi], bw[ni], acc[mi][ni]);
    }
    #pragma unroll
    for (int mi = 0; mi < 4; ++mi) {
        #pragma unroll
        for (int r = 0; r < 4; ++r) {
            int grow = m0 + wm * 64 + mi * 16 + quad * 4 + r;
            int wi2 = grow >> 7, t = grow & 127;
            int b = wi2 >> 8, wd = (wi2 >> 6) & 3, wh = (wi2 >> 3) & 7, ww = wi2 & 7;
            int td = t >> 6, th = (t >> 3) & 7, tw = t & 7;
            int d = (wd * 2 + td + 1) & 7, h = (wh * 8 + th + 4) & 63, w = (ww * 8 + tw + 4) & 63;
            long di = (((long)((b * 8 + d) * 64 + h)) * 64 + w) * 128;
            #pragma unroll
            for (int ni = 0; ni < 4; ++ni) {
                int gcol = wn * 64 + ni * 16 + li;
                x1[di + gcol] = f2b(acc[mi][ni][r] + proj_b[gcol] + x[di + gcol]);
            }
        }
    }
}

// ---------------------------------------------------------------------------
// K5: fused MLP: LN2 + FC1 + exact gelu + FC2 + residual; f32 output.
// Weights direct from global bf16 (wf1 @ wf, wf2 @ wf+65536). 10 syncs.
// ---------------------------------------------------------------------------
__global__ __launch_bounds__(256) void k5_mlp(
    const ushort* __restrict__ x1, const float* __restrict__ g2,
    const float* __restrict__ be2, const ushort* __restrict__ wf1,
    const float* __restrict__ fc1_b, const ushort* __restrict__ wf2,
    const float* __restrict__ fc2_b, float* __restrict__ out)
{
    __shared__ __align__(16) ushort xs[64][136];
    __shared__ __align__(16) ushort hs[64][136];
    __shared__ float redS[4][64];
    __shared__ float redQ[4][64];
    int tid = threadIdx.x;
    int m0 = blockIdx.x * 64;
    int wv = tid >> 6, lane = tid & 63, li = lane & 15, quad = lane >> 4;
    int wm = wv >> 1, wn = wv & 1;
    {   // LN2
        int token = tid & 63, part = tid >> 6;
        float vals[32];
        float s = 0.f, q = 0.f;
        #pragma unroll
        for (int i = 0; i < 4; ++i) {
            uint4 u = *(const uint4*)&x1[(long)(m0 + token) * 128 + part * 32 + i * 8];
            const ushort* p = (const ushort*)&u;
            #pragma unroll
            for (int j = 0; j < 8; ++j) { float f = b2f(p[j]); vals[i * 8 + j] = f; s += f; q += f * f; }
        }
        redS[part][token] = s; redQ[part][token] = q;
        __syncthreads();
        float st = 0.f, qt = 0.f;
        #pragma unroll
        for (int p2 = 0; p2 < 4; ++p2) { st += redS[p2][token]; qt += redQ[p2][token]; }
        float mean = st * (1.f / 128.f);
        float rstd = rsqrtf(qt * (1.f / 128.f) - mean * mean + 1e-5f);
        #pragma unroll
        for (int i = 0; i < 4; ++i) {
            ushort packed[8];
            #pragma unroll
            for (int j = 0; j < 8; ++j) {
                int c = part * 32 + i * 8 + j;
                packed[j] = f2b((vals[i * 8 + j] - mean) * rstd * g2[c] + be2[c]);
            }
            *(uint4*)&xs[token][part * 32 + i * 8] = *(uint4*)packed;
        }
    }
    __syncthreads();

    f32x4 yacc[2][4] = {};
    for (int hc = 0; hc < 4; ++hc) {
        f32x4 hacc[2][4] = {};
        #pragma unroll
        for (int kk = 0; kk < 4; ++kk) {          // GEMM1, no syncs
            s16x8 a[2], bw[4];
            #pragma unroll
            for (int mi = 0; mi < 2; ++mi)
                a[mi] = *(const s16x8*)&xs[wm * 32 + mi * 16 + li][kk * 32 + quad * 8];
            #pragma unroll
            for (int ni = 0; ni < 4; ++ni)
                bw[ni] = *(const s16x8*)&wf1[(long)(hc * 128 + wn * 64 + ni * 16 + li) * 128
                                             + kk * 32 + quad * 8];
            #pragma unroll
            for (int mi = 0; mi < 2; ++mi)
                #pragma unroll
                for (int ni = 0; ni < 4; ++ni)
                    hacc[mi][ni] = MFMA(a[mi], bw[ni], hacc[mi][ni]);
        }
        #pragma unroll
        for (int mi = 0; mi < 2; ++mi)            // exact gelu -> hs (bf16)
            #pragma unroll
            for (int ni = 0; ni < 4; ++ni) {
                int col = wn * 64 + ni * 16 + li;
                float bb = fc1_b[hc * 128 + col];
                #pragma unroll
                for (int r = 0; r < 4; ++r) {
                    int row = wm * 32 + mi * 16 + quad * 4 + r;
                    float v = hacc[mi][ni][r] + bb;
                    hs[row][col] = f2b(0.5f * v * (1.f + erff(v * 0.70710678118f)));
                }
            }
        __syncthreads();
        #pragma unroll
        for (int kk = 0; kk < 4; ++kk) {          // GEMM2, no syncs
            s16x8 a[2], bw[4];
            #pragma unroll
            for (int mi = 0; mi < 2; ++mi)
                a[mi] = *(const s16x8*)&hs[wm * 32 + mi * 16 + li][kk * 32 + quad * 8];
            #pragma unroll
            for (int ni = 0; ni < 4; ++ni)
                bw[ni] = *(const s16x8*)&wf2[(long)(wn * 64 + ni * 16 + li) * 512
                                             + hc * 128 + kk * 32 + quad * 8];
            #pragma unroll
            for (int mi = 0; mi < 2; ++mi)
                #pragma unroll
                for (int ni = 0; ni < 4; ++ni)
                    yacc[mi][ni] = MFMA(a[mi], bw[ni], yacc[mi][ni]);
        }
        __syncthreads();                           // before next hc overwrites hs
    }
    #pragma unroll
    for (int mi = 0; mi < 2; ++mi)
        #pragma unroll
        for (int ni = 0; ni < 4; ++ni) {
            int col = wn * 64 + ni * 16 + li;
            float fb = fc2_b[col];
            #pragma unroll
            for (int r = 0; r < 4; ++r) {
                int row = wm * 32 + mi * 16 + quad * 4 + r;
                long idx = (long)(m0 + row) * 128 + col;
                out[idx] = b2f(x1[idx]) + yacc[mi][ni][r] + fb;   // f32 store
            }
        }
}

// ---------------------------------------------------------------------------
// Buffers:
//   ws  [0 .. 50.33MB): qkv head-major (K2->K3); then x1 bf16 [0..16.8MB) (K4->K5)
//   ws  +33,554,432 B : fc1/fc2 bf16 weights (written by K0b AFTER K3; qkv dead)
//   d_out (33.5 MB f32): [0..16.8MB) attn-out bf16 scratch (K3->K4);
//         tail T = d_out+16.8MB: qkv_w/proj_w bf16 (65536) + bm table (2 MB)
//   K5 overwrites all of d_out with the final f32 result.
// ---------------------------------------------------------------------------
extern "C" void kernel_launch(void* const* d_in, const int* in_sizes, int n_in,
                              void* d_out, int out_size, void* d_ws, size_t ws_size,
                              hipStream_t stream)
{
    (void)in_sizes; (void)n_in; (void)out_size; (void)ws_size;
    const float* x      = (const float*)d_in[0];
    const float* qkv_w  = (const float*)d_in[1];
    const float* qkv_b  = (const float*)d_in[2];
    const float* proj_w = (const float*)d_in[3];
    const float* proj_b = (const float*)d_in[4];
    const float* rpb    = (const float*)d_in[5];
    const float* ln1_g  = (const float*)d_in[6];
    const float* ln1_b  = (const float*)d_in[7];
    const float* ln2_g  = (const float*)d_in[8];
    const float* ln2_b  = (const float*)d_in[9];
    const float* fc1_w  = (const float*)d_in[10];
    const float* fc1_b  = (const float*)d_in[11];
    const float* fc2_w  = (const float*)d_in[12];
    const float* fc2_b  = (const float*)d_in[13];
    float* out = (float*)d_out;

    ushort* qkvb = (ushort*)d_ws;                       // 50.33 MB head-major qkv
    ushort* x1b  = (ushort*)d_ws;                       // 16.8 MB (qkv dead)
    ushort* wf   = (ushort*)((char*)d_ws + 33554432);   // fc1/fc2 bf16 (after K3)
    ushort* aob  = (ushort*)d_out;                      // 16.8 MB attn scratch
    ushort* T    = (ushort*)d_out + 8388608;            // d_out tail: wq/wp + bm
    ushort* wq   = T;                                   // 49152
    ushort* wp   = T + 49152;                           // 16384
    ushort* bm   = T + 65536;                           // 1,048,576 (2 MB)

    hipLaunchKernelGGL(k0a_prep, dim3(320), dim3(256), 0, stream, qkv_w, proj_w, rpb, T);
    hipLaunchKernelGGL(k2_qkv,   dim3(512), dim3(256), 0, stream, x, ln1_g, ln1_b, wq, qkv_b, qkvb);
    hipLaunchKernelGGL(k3_attn,  dim3(4096), dim3(256), 0, stream, qkvb, bm, aob);
    hipLaunchKernelGGL(k0b_wconv, dim3(512), dim3(256), 0, stream, fc1_w, fc2_w, wf);
    hipLaunchKernelGGL(k4_proj,  dim3(512), dim3(256), 0, stream, aob, wp, proj_b, x, x1b);
    hipLaunchKernelGGL(k5_mlp,   dim3(1024), dim3(256), 0, stream,
                       x1b, ln2_g, ln2_b, wf, fc1_b, wf + 65536, fc2_b, out);
}

// Round 8
// 286.566 us; speedup vs baseline: 1.1492x; 1.0049x over previous
//
#include <hip/hip_runtime.h>
#include <math.h>

typedef short s16x8 __attribute__((ext_vector_type(8)));
typedef float f32x4 __attribute__((ext_vector_type(4)));

#define MFMA(a, b, c)   __builtin_amdgcn_mfma_f32_16x16x32_bf16(a, b, c, 0, 0, 0)

__device__ __forceinline__ float b2f(ushort u) {
    union { unsigned int i; float f; } v; v.i = ((unsigned int)u) << 16; return v.f;
}
__device__ __forceinline__ ushort f2b(float f) {
    union { float f; unsigned int i; } v; v.f = f;
    unsigned int r = v.i + 0x7fffu + ((v.i >> 16) & 1u);
    return (ushort)(r >> 16);
}
__device__ __forceinline__ float gelu_tanh(float v) {
    float u = 0.7978845608f * (v + 0.044715f * v * v * v);
    float e = __expf(-2.f * fabsf(u));
    float t = (1.f - e) / (1.f + e);            // tanh(|u|)
    t = (u < 0.f) ? -t : t;
    return 0.5f * v * (1.f + t);
}

// ---------------------------------------------------------------------------
// K0: all prep. blocks [0,192): qkv_w->wq; [192,256): proj_w->wp;
// [256,768): fc1/fc2->wf; [768,832): bias+mask table bm[cls][head][128][128].
// ---------------------------------------------------------------------------
__global__ __launch_bounds__(256) void k0_prep(
    const float* __restrict__ qkv_w, const float* __restrict__ proj_w,
    const float* __restrict__ fc1_w, const float* __restrict__ fc2_w,
    const float* __restrict__ rpb, ushort* __restrict__ wq,
    ushort* __restrict__ wp, ushort* __restrict__ wf, ushort* __restrict__ bm)
{
    int bid = blockIdx.x, tid = threadIdx.x;
    if (bid < 192) { int idx = bid * 256 + tid; wq[idx] = f2b(qkv_w[idx]); return; }
    if (bid < 256) { int idx = (bid - 192) * 256 + tid; wp[idx] = f2b(proj_w[idx]); return; }
    if (bid < 768) {
        int idx = (bid - 256) * 256 + tid;
        wf[idx] = f2b(idx < 65536 ? fc1_w[idx] : fc2_w[idx - 65536]);
        return;
    }
    int bi = bid - 768;                             // [0,64) = cls*8+head
    int cls = bi >> 3, head = bi & 7;
    int ed = (cls >> 2) & 1, eh = (cls >> 1) & 1, ew = cls & 1;
    int j = tid & 127;
    int tdj = j >> 6, thj = (j >> 3) & 7, twj = j & 7;
    int regj = (ed ? (tdj + 1) : 0) * 9
             + (eh ? ((thj < 4) ? 1 : 2) : 0) * 3
             + (ew ? ((twj < 4) ? 1 : 2) : 0);
    ushort* bmp = bm + (long)bi * 16384;
    for (int ii = 0; ii < 64; ++ii) {
        int i = (tid >> 7) * 64 + ii;
        int tdi = i >> 6, thi = (i >> 3) & 7, twi = i & 7;
        int regi = (ed ? (tdi + 1) : 0) * 9
                 + (eh ? ((thi < 4) ? 1 : 2) : 0) * 3
                 + (ew ? ((twi < 4) ? 1 : 2) : 0);
        int rpi = (tdi - tdj + 1) * 225 + (thi - thj + 7) * 15 + (twi - twj + 7);
        float v = rpb[rpi * 8 + head] + ((regi != regj) ? -100.f : 0.f);
        bmp[i * 128 + j] = f2b(v);
    }
}

// ---------------------------------------------------------------------------
// K2: fused LN1 + cyclic-shift + window gather + QKV GEMM.
// Output WINDOW-major: qkv[wi][mat][head][token][16] (strides 49152/16384/2048/16).
// ---------------------------------------------------------------------------
__global__ __launch_bounds__(256) void k2_qkv(
    const float* __restrict__ x, const float* __restrict__ g,
    const float* __restrict__ be, const ushort* __restrict__ wq,
    const float* __restrict__ qkv_b, ushort* __restrict__ qkv)
{
    __shared__ __align__(16) ushort As[128][136];
    int tid = threadIdx.x;
    int m0 = blockIdx.x * 128;
    {   // LN + shift + gather -> As (2 threads per row)
        int row = tid >> 1, half = tid & 1;
        int tk = m0 + row;
        int wi = tk >> 7, t = tk & 127;
        int b = wi >> 8, wd = (wi >> 6) & 3, wh = (wi >> 3) & 7, ww = wi & 7;
        int td = t >> 6, th = (t >> 3) & 7, tw = t & 7;
        int d = (wd * 2 + td + 1) & 7;
        int h = (wh * 8 + th + 4) & 63;
        int w = (ww * 8 + tw + 4) & 63;
        long src = (((long)((b * 8 + d) * 64 + h)) * 64 + w) * 128 + half * 64;
        float vals[64];
        float s = 0.f, q = 0.f;
        #pragma unroll
        for (int i = 0; i < 16; ++i) {
            float4 u = *(const float4*)&x[src + i * 4];
            vals[i * 4 + 0] = u.x; vals[i * 4 + 1] = u.y;
            vals[i * 4 + 2] = u.z; vals[i * 4 + 3] = u.w;
            s += u.x + u.y + u.z + u.w;
            q += u.x * u.x + u.y * u.y + u.z * u.z + u.w * u.w;
        }
        s += __shfl_xor(s, 1);
        q += __shfl_xor(q, 1);
        float mean = s * (1.f / 128.f);
        float rstd = rsqrtf(q * (1.f / 128.f) - mean * mean + 1e-5f);
        #pragma unroll
        for (int i = 0; i < 8; ++i) {
            ushort pk[8];
            #pragma unroll
            for (int jj = 0; jj < 8; ++jj) {
                int c = half * 64 + i * 8 + jj;
                pk[jj] = f2b((vals[i * 8 + jj] - mean) * rstd * g[c] + be[c]);
            }
            *(uint4*)&As[row][half * 64 + i * 8] = *(uint4*)pk;
        }
    }
    __syncthreads();
    int wv = tid >> 6, lane = tid & 63, li = lane & 15, quad = lane >> 4;
    int wm = wv >> 1, wn = wv & 1;
    long wibase = (long)(m0 >> 7) * 49152;
    for (int nb = 0; nb < 3; ++nb) {
        f32x4 acc[4][4] = {};
        for (int s = 0; s < 4; ++s) {
            s16x8 a[4], bw[4];
            #pragma unroll
            for (int mi = 0; mi < 4; ++mi)
                a[mi] = *(const s16x8*)&As[wm * 64 + mi * 16 + li][s * 32 + quad * 8];
            #pragma unroll
            for (int ni = 0; ni < 4; ++ni)
                bw[ni] = *(const s16x8*)&wq[(long)(nb * 128 + wn * 64 + ni * 16 + li) * 128
                                            + s * 32 + quad * 8];
            #pragma unroll
            for (int mi = 0; mi < 4; ++mi)
                #pragma unroll
                for (int ni = 0; ni < 4; ++ni)
                    acc[mi][ni] = MFMA(a[mi], bw[ni], acc[mi][ni]);
        }
        #pragma unroll
        for (int mi = 0; mi < 4; ++mi)
            #pragma unroll
            for (int ni = 0; ni < 4; ++ni) {
                int gcol = nb * 128 + wn * 64 + ni * 16 + li;
                int mat = gcol >> 7, hd = (gcol >> 4) & 7;
                float bias = qkv_b[gcol];
                float scale = (mat == 0) ? 0.25f : 1.f;   // SCALE = 16^-0.5
                long base2 = wibase + mat * 16384 + hd * 2048 + li;
                #pragma unroll
                for (int r = 0; r < 4; ++r) {
                    int trow = wm * 64 + mi * 16 + quad * 4 + r;
                    qkv[base2 + trow * 16] = f2b((acc[mi][ni][r] + bias) * scale);
                }
            }
    }
}

// ---------------------------------------------------------------------------
// K3: one block per WINDOW, 8 heads sequential. QK^T (16x16x32, d zero-padded),
// bias+mask table, softmax, PV. O held in registers across heads, then written
// in-place over the (dead) q-region of this window: ao[wi][token][128ch].
// ---------------------------------------------------------------------------
__global__ __launch_bounds__(256) void k3_attn(
    ushort* __restrict__ qkv, const ushort* __restrict__ bm)
{
    __shared__ __align__(16) ushort qs[128][40];
    __shared__ __align__(16) ushort ks[128][40];
    __shared__ __align__(16) ushort vt[16][136];
    __shared__ __align__(16) ushort ps[128][136];
    int wi = blockIdx.x;
    int wd = (wi >> 6) & 3, wh = (wi >> 3) & 7, ww = wi & 7;
    int cls = ((wd == 3) << 2) | ((wh == 7) << 1) | (ww == 7);
    int tid = threadIdx.x;
    int wv = tid >> 6, lane = tid & 63, li = lane & 15, quad = lane >> 4;
    long wbase = (long)wi * 49152;
    uint2 opk[8][2];
    for (int h = 0; h < 8; ++h) {
        __syncthreads();   // previous head's PV readers done before restage
        {   int token = tid >> 1, dd0 = (tid & 1) * 8;
            long tb = wbase + h * 2048 + token * 16 + dd0;
            uint4 qv = *(const uint4*)&qkv[tb];
            uint4 kv = *(const uint4*)&qkv[tb + 16384];
            uint4 vv = *(const uint4*)&qkv[tb + 32768];
            uint4 z = {0, 0, 0, 0};
            *(uint4*)&qs[token][dd0] = qv;
            *(uint4*)&ks[token][dd0] = kv;
            *(uint4*)&qs[token][16 + dd0] = z;
            *(uint4*)&ks[token][16 + dd0] = z;
            const ushort* pv = (const ushort*)&vv;
            #pragma unroll
            for (int j = 0; j < 8; ++j) vt[dd0 + j][token] = pv[j];
        }
        __syncthreads();
        f32x4 sacc[2][8] = {};
        s16x8 a[2];
        #pragma unroll
        for (int mi = 0; mi < 2; ++mi)
            a[mi] = *(const s16x8*)&qs[wv * 32 + mi * 16 + li][quad * 8];
        #pragma unroll
        for (int ni = 0; ni < 8; ++ni) {
            s16x8 bf = *(const s16x8*)&ks[ni * 16 + li][quad * 8];
            #pragma unroll
            for (int mi = 0; mi < 2; ++mi) sacc[mi][ni] = MFMA(a[mi], bf, sacc[mi][ni]);
        }
        long bmbase = (long)(cls * 8 + h) * 16384;
        #pragma unroll
        for (int mi = 0; mi < 2; ++mi) {
            #pragma unroll
            for (int r = 0; r < 4; ++r) {
                int i = wv * 32 + mi * 16 + quad * 4 + r;
                float sv[8];
                float rowmax = -1e30f;
                #pragma unroll
                for (int ni = 0; ni < 8; ++ni) {
                    float v = sacc[mi][ni][r] + b2f(bm[bmbase + i * 128 + ni * 16 + li]);
                    sv[ni] = v;
                    rowmax = fmaxf(rowmax, v);
                }
                #pragma unroll
                for (int m = 1; m < 16; m <<= 1) rowmax = fmaxf(rowmax, __shfl_xor(rowmax, m));
                float sum = 0.f;
                #pragma unroll
                for (int ni = 0; ni < 8; ++ni) { sv[ni] = __expf(sv[ni] - rowmax); sum += sv[ni]; }
                #pragma unroll
                for (int m = 1; m < 16; m <<= 1) sum += __shfl_xor(sum, m);
                float inv = 1.f / sum;
                #pragma unroll
                for (int ni = 0; ni < 8; ++ni) ps[i][ni * 16 + li] = f2b(sv[ni] * inv);
            }
        }
        __syncthreads();
        f32x4 pacc[2] = {};
        #pragma unroll
        for (int kk = 0; kk < 4; ++kk) {
            s16x8 bv = *(const s16x8*)&vt[li][kk * 32 + quad * 8];
            #pragma unroll
            for (int mi = 0; mi < 2; ++mi) {
                s16x8 ap = *(const s16x8*)&ps[wv * 32 + mi * 16 + li][kk * 32 + quad * 8];
                pacc[mi] = MFMA(ap, bv, pacc[mi]);
            }
        }
        #pragma unroll
        for (int mi = 0; mi < 2; ++mi) {
            opk[h][mi].x = (unsigned int)f2b(pacc[mi][0]) | ((unsigned int)f2b(pacc[mi][1]) << 16);
            opk[h][mi].y = (unsigned int)f2b(pacc[mi][2]) | ((unsigned int)f2b(pacc[mi][3]) << 16);
        }
    }
    // all q/k/v of this window consumed -> safe to overwrite q-region with O
    #pragma unroll
    for (int h = 0; h < 8; ++h)
        #pragma unroll
        for (int mi = 0; mi < 2; ++mi) {
            unsigned int w0 = opk[h][mi].x, w1 = opk[h][mi].y;
            #pragma unroll
            for (int r = 0; r < 4; ++r) {
                unsigned int word = (r < 2) ? w0 : w1;
                ushort v = (ushort)((word >> ((r & 1) * 16)) & 0xffff);
                int i = wv * 32 + mi * 16 + quad * 4 + r;
                qkv[wbase + (long)i * 128 + h * 16 + li] = v;
            }
        }
}

// ---------------------------------------------------------------------------
// K45: fused proj GEMM + bias + residual + LN2 + FC1 + gelu + FC2 + residual
// + window-reverse/unshift scattered f32 store. 64-token tile, 1024 blocks.
// ---------------------------------------------------------------------------
__global__ __launch_bounds__(256) void k45(
    const ushort* __restrict__ ao, const ushort* __restrict__ wp,
    const float* __restrict__ proj_b, const float* __restrict__ x,
    const float* __restrict__ g2, const float* __restrict__ be2,
    const ushort* __restrict__ wf1, const float* __restrict__ fc1_b,
    const ushort* __restrict__ wf2, const float* __restrict__ fc2_b,
    float* __restrict__ out)
{
    __shared__ __align__(16) ushort As[64][132];    // ao tile, later xs (LN2 out)
    __shared__ __align__(16) ushort x1t[64][132];   // x1 (bf16)
    __shared__ __align__(16) ushort hs[64][132];    // gelu(h) chunk
    __shared__ float redS[4][64];
    __shared__ float redQ[4][64];
    int tid = threadIdx.x;
    int b = blockIdx.x;
    int wi = b >> 1, half64 = b & 1;
    int wd = (wi >> 6) & 3, wh = (wi >> 3) & 7, ww = wi & 7;
    int bb = wi >> 8;
    long aobase = (long)wi * 49152 + half64 * 8192;
    #pragma unroll
    for (int i = 0; i < 4; ++i) {
        int slot = tid + i * 256;
        int row = slot >> 4, c8 = (slot & 15) * 8;
        *(uint4*)&As[row][c8] = *(const uint4*)&ao[aobase + row * 128 + c8];
    }
    __syncthreads();
    int wv = tid >> 6, lane = tid & 63, li = lane & 15, quad = lane >> 4;
    int wm = wv >> 1, wn = wv & 1;
    f32x4 acc[2][4] = {};
    for (int s = 0; s < 4; ++s) {
        s16x8 a[2], bw[4];
        #pragma unroll
        for (int mi = 0; mi < 2; ++mi)
            a[mi] = *(const s16x8*)&As[wm * 32 + mi * 16 + li][s * 32 + quad * 8];
        #pragma unroll
        for (int ni = 0; ni < 4; ++ni)
            bw[ni] = *(const s16x8*)&wp[(long)(wn * 64 + ni * 16 + li) * 128 + s * 32 + quad * 8];
        #pragma unroll
        for (int mi = 0; mi < 2; ++mi)
            #pragma unroll
            for (int ni = 0; ni < 4; ++ni)
                acc[mi][ni] = MFMA(a[mi], bw[ni], acc[mi][ni]);
    }
    // epilogue: residual add (f32 x) -> x1t (bf16)
    #pragma unroll
    for (int mi = 0; mi < 2; ++mi) {
        #pragma unroll
        for (int r = 0; r < 4; ++r) {
            int lrow = wm * 32 + mi * 16 + quad * 4 + r;
            int t = half64 * 64 + lrow;
            int td = t >> 6, th = (t >> 3) & 7, tw = t & 7;
            int d = (wd * 2 + td + 1) & 7, h = (wh * 8 + th + 4) & 63, w = (ww * 8 + tw + 4) & 63;
            long di = (((long)((bb * 8 + d) * 64 + h)) * 64 + w) * 128;
            #pragma unroll
            for (int ni = 0; ni < 4; ++ni) {
                int col = wn * 64 + ni * 16 + li;
                x1t[lrow][col] = f2b(acc[mi][ni][r] + proj_b[col] + x[di + col]);
            }
        }
    }
    __syncthreads();
    {   // LN2 from x1t -> xs (reuse As)
        int token = tid & 63, part = tid >> 6;
        float vals[32];
        float s = 0.f, q = 0.f;
        #pragma unroll
        for (int i = 0; i < 4; ++i) {
            uint4 u = *(const uint4*)&x1t[token][part * 32 + i * 8];
            const ushort* p = (const ushort*)&u;
            #pragma unroll
            for (int j = 0; j < 8; ++j) { float f = b2f(p[j]); vals[i * 8 + j] = f; s += f; q += f * f; }
        }
        redS[part][token] = s; redQ[part][token] = q;
        __syncthreads();
        float st = 0.f, qt = 0.f;
        #pragma unroll
        for (int p2 = 0; p2 < 4; ++p2) { st += redS[p2][token]; qt += redQ[p2][token]; }
        float mean = st * (1.f / 128.f);
        float rstd = rsqrtf(qt * (1.f / 128.f) - mean * mean + 1e-5f);
        #pragma unroll
        for (int i = 0; i < 4; ++i) {
            ushort packed[8];
            #pragma unroll
            for (int j = 0; j < 8; ++j) {
                int c = part * 32 + i * 8 + j;
                packed[j] = f2b((vals[i * 8 + j] - mean) * rstd * g2[c] + be2[c]);
            }
            *(uint4*)&As[token][part * 32 + i * 8] = *(uint4*)packed;
        }
    }
    __syncthreads();
    f32x4 yacc[2][4] = {};
    for (int hc = 0; hc < 4; ++hc) {
        f32x4 hacc[2][4] = {};
        #pragma unroll
        for (int kk = 0; kk < 4; ++kk) {
            s16x8 a[2], bw[4];
            #pragma unroll
            for (int mi = 0; mi < 2; ++mi)
                a[mi] = *(const s16x8*)&As[wm * 32 + mi * 16 + li][kk * 32 + quad * 8];
            #pragma unroll
            for (int ni = 0; ni < 4; ++ni)
                bw[ni] = *(const s16x8*)&wf1[(long)(hc * 128 + wn * 64 + ni * 16 + li) * 128
                                             + kk * 32 + quad * 8];
            #pragma unroll
            for (int mi = 0; mi < 2; ++mi)
                #pragma unroll
                for (int ni = 0; ni < 4; ++ni)
                    hacc[mi][ni] = MFMA(a[mi], bw[ni], hacc[mi][ni]);
        }
        #pragma unroll
        for (int mi = 0; mi < 2; ++mi)
            #pragma unroll
            for (int ni = 0; ni < 4; ++ni) {
                int col = wn * 64 + ni * 16 + li;
                float bbv = fc1_b[hc * 128 + col];
                #pragma unroll
                for (int r = 0; r < 4; ++r) {
                    int row = wm * 32 + mi * 16 + quad * 4 + r;
                    hs[row][col] = f2b(gelu_tanh(hacc[mi][ni][r] + bbv));
                }
            }
        __syncthreads();
        #pragma unroll
        for (int kk = 0; kk < 4; ++kk) {
            s16x8 a[2], bw[4];
            #pragma unroll
            for (int mi = 0; mi < 2; ++mi)
                a[mi] = *(const s16x8*)&hs[wm * 32 + mi * 16 + li][kk * 32 + quad * 8];
            #pragma unroll
            for (int ni = 0; ni < 4; ++ni)
                bw[ni] = *(const s16x8*)&wf2[(long)(wn * 64 + ni * 16 + li) * 512
                                             + hc * 128 + kk * 32 + quad * 8];
            #pragma unroll
            for (int mi = 0; mi < 2; ++mi)
                #pragma unroll
                for (int ni = 0; ni < 4; ++ni)
                    yacc[mi][ni] = MFMA(a[mi], bw[ni], yacc[mi][ni]);
        }
        __syncthreads();
    }
    #pragma unroll
    for (int mi = 0; mi < 2; ++mi) {
        #pragma unroll
        for (int r = 0; r < 4; ++r) {
            int lrow = wm * 32 + mi * 16 + quad * 4 + r;
            int t = half64 * 64 + lrow;
            int td = t >> 6, th = (t >> 3) & 7, tw = t & 7;
            int d = (wd * 2 + td + 1) & 7, h = (wh * 8 + th + 4) & 63, w = (ww * 8 + tw + 4) & 63;
            long di = (((long)((bb * 8 + d) * 64 + h)) * 64 + w) * 128;
            #pragma unroll
            for (int ni = 0; ni < 4; ++ni) {
                int col = wn * 64 + ni * 16 + li;
                out[di + col] = b2f(x1t[lrow][col]) + yacc[mi][ni][r] + fc2_b[col];
            }
        }
    }
}

// ---------------------------------------------------------------------------
// ws layout (needs ~52.9 MB):
//   [0 .. 50.33MB): qkv window-major [wi][mat][head][tok][16]; K3 overwrites
//                   each window's q-region in-place with attn-out [wi][tok][128].
//   tail: wq 96KB | wp 32KB | wf 256KB | bm 2MB.
// d_out holds ONLY the final f32 output (no scratch -> no races).
// ---------------------------------------------------------------------------
extern "C" void kernel_launch(void* const* d_in, const int* in_sizes, int n_in,
                              void* d_out, int out_size, void* d_ws, size_t ws_size,
                              hipStream_t stream)
{
    (void)in_sizes; (void)n_in; (void)out_size; (void)ws_size;
    const float* x      = (const float*)d_in[0];
    const float* qkv_w  = (const float*)d_in[1];
    const float* qkv_b  = (const float*)d_in[2];
    const float* proj_w = (const float*)d_in[3];
    const float* proj_b = (const float*)d_in[4];
    const float* rpb    = (const float*)d_in[5];
    const float* ln1_g  = (const float*)d_in[6];
    const float* ln1_b  = (const float*)d_in[7];
    const float* ln2_g  = (const float*)d_in[8];
    const float* ln2_b  = (const float*)d_in[9];
    const float* fc1_w  = (const float*)d_in[10];
    const float* fc1_b  = (const float*)d_in[11];
    const float* fc2_w  = (const float*)d_in[12];
    const float* fc2_b  = (const float*)d_in[13];
    float* out = (float*)d_out;

    ushort* qkvb = (ushort*)d_ws;                       // 50.33 MB
    ushort* wq   = (ushort*)((char*)d_ws + 50331648);   // 49152 elems
    ushort* wp   = wq + 49152;                          // 16384
    ushort* wf   = wp + 16384;                          // 131072
    ushort* bm   = wf + 131072;                         // 1048576

    hipLaunchKernelGGL(k0_prep, dim3(832), dim3(256), 0, stream,
                       qkv_w, proj_w, fc1_w, fc2_w, rpb, wq, wp, wf, bm);
    hipLaunchKernelGGL(k2_qkv, dim3(512), dim3(256), 0, stream,
                       x, ln1_g, ln1_b, wq, qkv_b, qkvb);
    hipLaunchKernelGGL(k3_attn, dim3(512), dim3(256), 0, stream, qkvb, bm);
    hipLaunchKernelGGL(k45, dim3(1024), dim3(256), 0, stream,
                       qkvb, wp, proj_b, x, ln2_g, ln2_b,
                       wf, fc1_b, wf + 65536, fc2_b, out);
}